// Round 1
// 67.133 us; speedup vs baseline: 1.0004x; 1.0004x over previous
//
#include <hip/hip_runtime.h>

// FM second-order term, v7: prep kernel + swapped-operand MFMA, zero big-LDS.
//   out[b] = sum_e (sum_f x[b,f]*W[f,e])^2 - sum_f x[b,f]^2 * s[f]
//
// prep (13 blocks, once per iteration into d_ws):
//   wt[64][224] = W^T * 2^13 (fp16, zero-padded f in [200,224)), sf[224] = s[f].
// main (B/16 = 1024 blocks x 256 thr, 4 blocks/CU -> 4 waves/SIMD):
//   wave w = e-tile w. MFMA computes D[e][b] = (W^T)·(X^T):
//     A-frag = wt rows (16B contiguous loads from ws, L1/L2-resident),
//     B-frag = X row lm, 8 consecutive floats -> cvt half8 in-register.
//   D: col=lm=b, row=lq*4+r2=e_local  =>  both p and q land on lane lm.
//   q (fp32, wave 0 only) from the same x values; 320 B LDS combine, 1 barrier.

constexpr int F  = 200;
constexpr int KP = 224;             // padded K (7 x 32)
constexpr float WSCALE = 8192.0f;   // 2^13 (exact)
constexpr float OSCALE = 1.0f / (WSCALE * WSCALE);  // 2^-26 (exact)

typedef _Float16 half8 __attribute__((ext_vector_type(8)));
typedef float floatx4 __attribute__((ext_vector_type(4)));

__global__ __launch_bounds__(256)
void fm_prep(const float* __restrict__ W, _Float16* __restrict__ wt,
             float* __restrict__ sf)
{
    const int t = threadIdx.x;
    const int i = (int)blockIdx.x * 256 + t;          // 3200 float4 total
    if (i < 3200) {
        floatx4 w4 = ((const floatx4*)W)[i];
        const int f  = i >> 4;                        // 16 float4 per f-row
        const int e0 = (i & 15) * 4;
        float ss = w4.x*w4.x + w4.y*w4.y + w4.z*w4.z + w4.w*w4.w;
        ss += __shfl_xor(ss, 1, 64);                  // row f = 16-lane group
        ss += __shfl_xor(ss, 2, 64);
        ss += __shfl_xor(ss, 4, 64);
        ss += __shfl_xor(ss, 8, 64);
        if ((t & 15) == 0) sf[f] = ss;
        wt[(e0 + 0) * KP + f] = (_Float16)(w4.x * WSCALE);
        wt[(e0 + 1) * KP + f] = (_Float16)(w4.y * WSCALE);
        wt[(e0 + 2) * KP + f] = (_Float16)(w4.z * WSCALE);
        wt[(e0 + 3) * KP + f] = (_Float16)(w4.w * WSCALE);
    }
    if (blockIdx.x == 12 && t >= 128) {               // zero pad f in [200,224)
        const int j = t - 128;
        half8 z = {};
        for (int c = j; c < 192; c += 128) {          // 64 e-rows x 3 half8
            int e = c / 3, part = c - 3 * e;
            *(half8*)(wt + e * KP + 200 + part * 8) = z;
        }
        if (j < 24) sf[200 + j] = 0.f;
    }
}

__global__ __launch_bounds__(256, 4)
void fm_v7(const float* __restrict__ X, const _Float16* __restrict__ wt,
           const float* __restrict__ sf, float* __restrict__ out)
{
    __shared__ float p_lds[4][16];
    __shared__ float q_lds[16];

    const int t    = threadIdx.x;
    const int lane = t & 63;
    const int w    = __builtin_amdgcn_readfirstlane(t >> 6);  // e-tile index
    const int lm   = lane & 15, lq = lane >> 4;
    const int row  = (int)blockIdx.x * 16 + lm;

    const float*    xr = X + (size_t)row * F;
    const _Float16* wr = wt + (16 * w + lm) * KP + lq * 8;    // A-frag base

    floatx4 acc = {};
    float q = 0.f;
    #pragma unroll
    for (int kk = 0; kk < 7; ++kk) {                  // K = 224
        half8 a = *(const half8*)(wr + kk * 32);      // W^T[16w+lm][k], 16 B
        half8 b;
        if (kk < 6 || lq == 0) {                      // k >= 200 is masked out
            const int k0 = kk * 32 + lq * 8;
            floatx4 x0 = *(const floatx4*)(xr + k0);
            floatx4 x1 = *(const floatx4*)(xr + k0 + 4);
            if (w == 0) {                             // q only needed once
                floatx4 s0 = *(const floatx4*)(sf + k0);
                floatx4 s1 = *(const floatx4*)(sf + k0 + 4);
                q += x0.x*x0.x*s0.x + x0.y*x0.y*s0.y + x0.z*x0.z*s0.z + x0.w*x0.w*s0.w
                   + x1.x*x1.x*s1.x + x1.y*x1.y*s1.y + x1.z*x1.z*s1.z + x1.w*x1.w*s1.w;
            }
            b[0] = (_Float16)x0.x; b[1] = (_Float16)x0.y;
            b[2] = (_Float16)x0.z; b[3] = (_Float16)x0.w;
            b[4] = (_Float16)x1.x; b[5] = (_Float16)x1.y;
            b[6] = (_Float16)x1.z; b[7] = (_Float16)x1.w;
        } else {
            b = (half8){};
        }
        acc = __builtin_amdgcn_mfma_f32_16x16x32_f16(a, b, acc, 0, 0, 0);
    }

    // p = sum over this wave's 16 e's of y'^2, for row b = lm
    float p = acc[0]*acc[0] + acc[1]*acc[1] + acc[2]*acc[2] + acc[3]*acc[3];
    p += __shfl_xor(p, 16, 64);                       // reduce over lq (e rows)
    p += __shfl_xor(p, 32, 64);
    if (w == 0) {
        q += __shfl_xor(q, 16, 64);                   // reduce over lq (k chunks)
        q += __shfl_xor(q, 32, 64);
    }
    if (lq == 0) {
        p_lds[w][lm] = p;
        if (w == 0) q_lds[lm] = q;
    }
    __syncthreads();                                  // only barrier
    if (t < 16) {
        float r = (p_lds[0][t] + p_lds[1][t] + p_lds[2][t] + p_lds[3][t]) * OSCALE
                - q_lds[t];
        out[(size_t)blockIdx.x * 16 + t] = r;
    }
}

extern "C" void kernel_launch(void* const* d_in, const int* in_sizes, int n_in,
                              void* d_out, int out_size, void* d_ws, size_t ws_size,
                              hipStream_t stream) {
    const float* X = (const float*)d_in[0];   // [16384, 200] fp32
    const float* W = (const float*)d_in[1];   // [200, 64] fp32
    float* out = (float*)d_out;               // [16384, 1] fp32

    _Float16* wt = (_Float16*)d_ws;                               // 28672 B
    float*    sf = (float*)((char*)d_ws + 64 * KP * sizeof(_Float16));

    const int B = in_sizes[0] / F;            // 16384
    fm_prep<<<13, 256, 0, stream>>>(W, wt, sf);
    fm_v7<<<B / 16, 256, 0, stream>>>(X, wt, sf, out);
}